// Round 7
// baseline (1085.494 us; speedup 1.0000x reference)
//
#include <hip/hip_runtime.h>
#include <hip/hip_bf16.h>

// DRew-GIN: N=50000, E=800000, D=128, L=3, NU=1.
// R7: split architecture. High-occupancy LDS-free gather kernel (degree-sorted
//     worklist, 4-deep uint4 pipeline) -> bf16 agg; GEMM kernel reads A-frags
//     directly from global (b_lds only, 4 blocks/CU).

#define NODES 50000
#define EDGES 800000
#define DIM   128
#define ND    ((long)NODES * DIM)
#define NB3   (3 * NODES)            // buckets: d*3 + (k-1)
#define NPART 8
#define PSIZE (NODES / NPART)
#define NROWP 50048                  // row-padded tensors (tail tile slack)

typedef __attribute__((ext_vector_type(8))) short  bf16x8;
typedef __attribute__((ext_vector_type(4))) float  f32x4;

#define LDS_STRIDE 136   // bf16 elements; 272B rows

// ---------------------------------------------------------------------------
__global__ __launch_bounds__(256) void convw_kernel(
    const float* __restrict__ Ws, const float* __restrict__ Wk,
    __hip_bfloat16* __restrict__ WT) {
  int m = blockIdx.x;  // 0..11
  const float* src = (m < 3) ? (Ws + (long)m * 16384) : (Wk + (long)(m - 3) * 16384);
  __hip_bfloat16* dst = WT + (long)m * 16384;
  for (int idx = threadIdx.x; idx < 16384; idx += 256) {
    int k = idx >> 7, n = idx & 127;
    dst[n * 128 + k] = __float2bfloat16(src[idx]);
  }
}

__global__ __launch_bounds__(256) void x2b_kernel(
    const float4* __restrict__ xin, uint2* __restrict__ xbo, long n4) {
  long i = (long)blockIdx.x * 256 + threadIdx.x;
  if (i >= n4) return;
  float4 v = xin[i];
  union { __hip_bfloat16 h[4]; uint2 u; } pk;
  pk.h[0] = __float2bfloat16(v.x); pk.h[1] = __float2bfloat16(v.y);
  pk.h[2] = __float2bfloat16(v.z); pk.h[3] = __float2bfloat16(v.w);
  xbo[i] = pk.u;
}

// Zero the dummy row (index NODES) of the three gather-source shadows.
__global__ __launch_bounds__(256) void zrow_kernel(
    __hip_bfloat16* __restrict__ xb0, __hip_bfloat16* __restrict__ xb1,
    __hip_bfloat16* __restrict__ xb2) {
  int i = threadIdx.x;
  if (i < DIM) {
    xb0[(long)NODES * DIM + i] = __float2bfloat16(0.f);
    xb1[(long)NODES * DIM + i] = __float2bfloat16(0.f);
    xb2[(long)NODES * DIM + i] = __float2bfloat16(0.f);
  }
}

// ---------------------------------------------------------------------------
// CSR build (pad-to-4) -- unchanged from R6.
__global__ __launch_bounds__(256) void hist_kernel(
    const int* __restrict__ ei, const int* __restrict__ attr,
    int* __restrict__ counts, int E) {
  int e = blockIdx.x * 256 + threadIdx.x;
  if (e >= E) return;
  atomicAdd(&counts[ei[E + e] * 3 + (attr[e] - 1)], 1);
}

__global__ __launch_bounds__(256) void scan_a_kernel(
    const int* __restrict__ counts, int* __restrict__ partial,
    int* __restrict__ blocksums, int n) {
  __shared__ int tmp[256];
  int gid = blockIdx.x * 256 + threadIdx.x;
  int v = (gid < n) ? ((counts[gid] + 3) & ~3) : 0;
  tmp[threadIdx.x] = v;
  __syncthreads();
  for (int off = 1; off < 256; off <<= 1) {
    int t = (threadIdx.x >= off) ? tmp[threadIdx.x - off] : 0;
    __syncthreads();
    tmp[threadIdx.x] += t;
    __syncthreads();
  }
  if (gid < n) partial[gid] = tmp[threadIdx.x] - v;
  if (threadIdx.x == 255) blocksums[blockIdx.x] = tmp[255];
}

__global__ __launch_bounds__(256) void scan_b_kernel(int* __restrict__ bs, int nb) {
  __shared__ int tmp[256];
  __shared__ int carry;
  if (threadIdx.x == 0) carry = 0;
  __syncthreads();
  for (int base = 0; base < nb; base += 256) {
    int gid = base + threadIdx.x;
    int v = (gid < nb) ? bs[gid] : 0;
    tmp[threadIdx.x] = v;
    __syncthreads();
    for (int off = 1; off < 256; off <<= 1) {
      int t = (threadIdx.x >= off) ? tmp[threadIdx.x - off] : 0;
      __syncthreads();
      tmp[threadIdx.x] += t;
      __syncthreads();
    }
    if (gid < nb) bs[gid] = tmp[threadIdx.x] - v + carry;
    __syncthreads();
    if (threadIdx.x == 0) carry += tmp[255];
    __syncthreads();
  }
}

__global__ __launch_bounds__(256) void scan_c_kernel(
    int* __restrict__ rowptr, int* __restrict__ cursor,
    const int* __restrict__ bs, int* __restrict__ csr, int n) {
  int gid = blockIdx.x * 256 + threadIdx.x;
  if (gid >= n) return;
  int cnt = cursor[gid];
  int pcnt = (cnt + 3) & ~3;
  int val = rowptr[gid] + bs[blockIdx.x];
  rowptr[gid] = val;
  cursor[gid] = val;
  for (int i = cnt; i < pcnt; ++i) csr[val + i] = NODES;
  if (gid == n - 1) rowptr[n] = val + pcnt;
}

__global__ __launch_bounds__(256) void fill_kernel(
    const int* __restrict__ ei, const int* __restrict__ attr,
    int* __restrict__ cursor, int* __restrict__ csr_src, int E) {
  int p = blockIdx.x & (NPART - 1);
  int chunk = blockIdx.x >> 3;
  int e = chunk * 256 + threadIdx.x;
  if (e >= E) return;
  int d = ei[E + e];
  int lo = p * PSIZE;
  if (d < lo || d >= lo + PSIZE) return;
  int pos = atomicAdd(&cursor[d * 3 + (attr[e] - 1)], 1);
  csr_src[pos] = ei[e];
}

// ---------------------------------------------------------------------------
// Degree sort: counting sort of buckets by padded size (big-first), per km1.
__global__ __launch_bounds__(256) void dhist_kernel(
    const int* __restrict__ rowptr, int* __restrict__ dhist) {
  int b = blockIdx.x * 256 + threadIdx.x;
  if (b >= NB3) return;
  int c = (rowptr[b + 1] - rowptr[b]) >> 2;
  if (c > 63) c = 63;
  atomicAdd(&dhist[(b % 3) * 64 + c], 1);
}

__global__ void dscan_kernel(const int* __restrict__ dhist, int* __restrict__ dcur) {
  if (threadIdx.x == 0 && blockIdx.x == 0) {
    for (int km1 = 0; km1 < 3; ++km1) {
      int acc = km1 * NODES;
      for (int c = 63; c >= 0; --c) {        // big buckets first in worklist
        dcur[km1 * 64 + c] = acc;
        acc += dhist[km1 * 64 + c];
      }
    }
  }
}

__global__ __launch_bounds__(256) void dfill_kernel(
    const int* __restrict__ rowptr, int* __restrict__ dcur, int* __restrict__ wl) {
  int b = blockIdx.x * 256 + threadIdx.x;
  if (b >= NB3) return;
  int c = (rowptr[b + 1] - rowptr[b]) >> 2;
  if (c > 63) c = 63;
  int pos = atomicAdd(&dcur[(b % 3) * 64 + c], 1);
  wl[pos] = b;
}

// ---------------------------------------------------------------------------
// Gather: one 16-lane group per worklist bucket. No LDS. 4-deep uint4 pipeline.
// wl[km1*N ..] holds buckets with key%3==km1, degree-sorted. nwork=(t+1)*N.
__global__ __launch_bounds__(256) void gather_kernel(
    const __hip_bfloat16* __restrict__ s0,   // source for km1=0
    const __hip_bfloat16* __restrict__ s1,   // km1=1
    const __hip_bfloat16* __restrict__ s2,   // km1=2
    const int* __restrict__ rowptr, const int* __restrict__ csr,
    const int* __restrict__ wl,
    __hip_bfloat16* __restrict__ ag0, __hip_bfloat16* __restrict__ ag1,
    __hip_bfloat16* __restrict__ ag2, int nwork) {
  int group = (blockIdx.x * 256 + threadIdx.x) >> 4;
  int lane16 = threadIdx.x & 15;
  if (group >= nwork) return;
  int b = wl[group];
  int d = b / 3;
  int km1 = b - d * 3;
  const __hip_bfloat16* xb = (km1 == 0) ? s0 : ((km1 == 1) ? s1 : s2);
  __hip_bfloat16* ag = (km1 == 0) ? ag0 : ((km1 == 1) ? ag1 : ag2);
  int beg = rowptr[b], end = rowptr[b + 1];   // (end-beg)%4 == 0
  float a0 = 0.f, a1 = 0.f, a2 = 0.f, a3 = 0.f,
        a4 = 0.f, a5 = 0.f, a6 = 0.f, a7 = 0.f;
  for (int base = beg; base < end; base += 16) {
    int idxv = csr[base + lane16];            // slack-allocated
    int cnt = end - base; if (cnt > 16) cnt = 16;
    for (int j = 0; j < cnt; j += 4) {
      int q0 = __shfl(idxv, j + 0, 16);
      int q1 = __shfl(idxv, j + 1, 16);
      int q2 = __shfl(idxv, j + 2, 16);
      int q3 = __shfl(idxv, j + 3, 16);
      uint4 v0 = *(const uint4*)(xb + (long)q0 * DIM + lane16 * 8);
      uint4 v1 = *(const uint4*)(xb + (long)q1 * DIM + lane16 * 8);
      uint4 v2 = *(const uint4*)(xb + (long)q2 * DIM + lane16 * 8);
      uint4 v3 = *(const uint4*)(xb + (long)q3 * DIM + lane16 * 8);
      a0 += __uint_as_float(v0.x << 16) + __uint_as_float(v1.x << 16)
          + __uint_as_float(v2.x << 16) + __uint_as_float(v3.x << 16);
      a1 += __uint_as_float(v0.x & 0xffff0000u) + __uint_as_float(v1.x & 0xffff0000u)
          + __uint_as_float(v2.x & 0xffff0000u) + __uint_as_float(v3.x & 0xffff0000u);
      a2 += __uint_as_float(v0.y << 16) + __uint_as_float(v1.y << 16)
          + __uint_as_float(v2.y << 16) + __uint_as_float(v3.y << 16);
      a3 += __uint_as_float(v0.y & 0xffff0000u) + __uint_as_float(v1.y & 0xffff0000u)
          + __uint_as_float(v2.y & 0xffff0000u) + __uint_as_float(v3.y & 0xffff0000u);
      a4 += __uint_as_float(v0.z << 16) + __uint_as_float(v1.z << 16)
          + __uint_as_float(v2.z << 16) + __uint_as_float(v3.z << 16);
      a5 += __uint_as_float(v0.z & 0xffff0000u) + __uint_as_float(v1.z & 0xffff0000u)
          + __uint_as_float(v2.z & 0xffff0000u) + __uint_as_float(v3.z & 0xffff0000u);
      a6 += __uint_as_float(v0.w << 16) + __uint_as_float(v1.w << 16)
          + __uint_as_float(v2.w << 16) + __uint_as_float(v3.w << 16);
      a7 += __uint_as_float(v0.w & 0xffff0000u) + __uint_as_float(v1.w & 0xffff0000u)
          + __uint_as_float(v2.w & 0xffff0000u) + __uint_as_float(v3.w & 0xffff0000u);
    }
  }
  union { __hip_bfloat16 h[8]; uint4 u; } pk;
  pk.h[0] = __float2bfloat16(a0); pk.h[1] = __float2bfloat16(a1);
  pk.h[2] = __float2bfloat16(a2); pk.h[3] = __float2bfloat16(a3);
  pk.h[4] = __float2bfloat16(a4); pk.h[5] = __float2bfloat16(a5);
  pk.h[6] = __float2bfloat16(a6); pk.h[7] = __float2bfloat16(a7);
  *(uint4*)(ag + (long)d * DIM + lane16 * 8) = pk.u;
}

// ---------------------------------------------------------------------------
// Layer GEMM: out = (1+eps)relu(xb@Ws+bs) + sum relu(ag@Wk+bk); xn = xt+relu(out).
// A-fragments read directly from global bf16 (agg / shadow); only B staged in LDS.
__global__ __launch_bounds__(256, 4) void lgemm_kernel(
    const float* __restrict__ xt,
    const __hip_bfloat16* __restrict__ xbSelf,
    const __hip_bfloat16* __restrict__ ag0,
    const __hip_bfloat16* __restrict__ ag1,
    const __hip_bfloat16* __restrict__ ag2,
    const __hip_bfloat16* __restrict__ WT,
    const float* __restrict__ bs_t,
    const float* __restrict__ bk_t,
    const float* __restrict__ epsp,
    float* __restrict__ xn,
    __hip_bfloat16* __restrict__ xnb,
    int t) {
  __shared__ __hip_bfloat16 b_lds[128 * LDS_STRIDE];  // 34816 B

  int tid = threadIdx.x;
  long row0 = (long)blockIdx.x * 64;
  int wave = tid >> 6, lane = tid & 63;
  int l15 = lane & 15, q = lane >> 4;
  long arow = row0 + wave * 16 + l15;          // A-frag row (< NROWP by padding)

  const __hip_bfloat16* Asrc[4] = {xbSelf, ag0, ag1, ag2};
  f32x4 out[8];

  for (int p = 0; p <= t + 1; ++p) {
    if (p > 0) __syncthreads();                // b_lds reuse
    // Prefetch A fragments (4 x uint4, native MFMA A layout).
    const __hip_bfloat16* Am = Asrc[p];
    uint4 af[4];
#pragma unroll
    for (int k0i = 0; k0i < 4; ++k0i)
      af[k0i] = *(const uint4*)(Am + arow * DIM + k0i * 32 + 8 * q);
    // Stage weight matrix -> b_lds.
    const __hip_bfloat16* W = (p == 0) ? (WT + (long)t * 16384)
                                       : (WT + (long)(3 + t * 3 + (p - 1)) * 16384);
    {
      const uint4* bq = (const uint4*)W;
#pragma unroll
      for (int i = 0; i < 8; ++i) {
        int idx = tid + 256 * i;
        int n = idx >> 4, k8 = idx & 15;
        uint4 v = bq[idx];
        *(uint4*)(b_lds + n * LDS_STRIDE + k8 * 8) = v;
      }
    }
    __syncthreads();

    f32x4 acc[8] = {};
#pragma unroll
    for (int k0i = 0; k0i < 4; ++k0i) {
      bf16x8 a = __builtin_bit_cast(bf16x8, af[k0i]);
#pragma unroll
      for (int j = 0; j < 8; ++j) {
        bf16x8 bfr = *(const bf16x8*)(b_lds + (16 * j + l15) * LDS_STRIDE + k0i * 32 + 8 * q);
        acc[j] = __builtin_amdgcn_mfma_f32_16x16x32_bf16(a, bfr, acc[j], 0, 0, 0);
      }
    }
    if (p == 0) {
      float sc = 1.0f + *epsp;
#pragma unroll
      for (int j = 0; j < 8; ++j) {
        float b = bs_t[16 * j + l15];
#pragma unroll
        for (int r = 0; r < 4; ++r) out[j][r] = sc * fmaxf(acc[j][r] + b, 0.f);
      }
    } else {
      const float* bb = bk_t + (p - 1) * 128;
#pragma unroll
      for (int j = 0; j < 8; ++j) {
        float b = bb[16 * j + l15];
#pragma unroll
        for (int r = 0; r < 4; ++r) out[j][r] += fmaxf(acc[j][r] + b, 0.f);
      }
    }
  }

  // Epilogue: xn = xt + relu(out); xnb = bf16(xn).
  long rbase = row0 + wave * 16 + q * 4;
#pragma unroll
  for (int j = 0; j < 8; ++j) {
    int col = 16 * j + l15;
#pragma unroll
    for (int r = 0; r < 4; ++r) {
      long grow = rbase + r;
      if (grow < NODES) {
        float v = xt[grow * DIM + col] + fmaxf(out[j][r], 0.f);
        xn[grow * DIM + col] = v;
        xnb[grow * DIM + col] = __float2bfloat16(v);
      }
    }
  }
}

// ---------------------------------------------------------------------------
extern "C" void kernel_launch(void* const* d_in, const int* in_sizes, int n_in,
                              void* d_out, int out_size, void* d_ws, size_t ws_size,
                              hipStream_t stream) {
  const float* x    = (const float*)d_in[0];
  const int*   ei   = (const int*)d_in[1];
  const int*   attr = (const int*)d_in[2];
  const float* Ws   = (const float*)d_in[3];
  const float* bs   = (const float*)d_in[4];
  const float* Wk   = (const float*)d_in[5];
  const float* bk   = (const float*)d_in[6];
  const float* eps  = (const float*)d_in[7];
  float* out = (float*)d_out;

  char* ws = (char*)d_ws;
  size_t off = 0;
  auto alloc = [&](size_t bytes) { char* p = ws + off; off += (bytes + 255) & ~(size_t)255; return p; };
  const size_t ROWB = (size_t)NROWP * DIM * 2;   // bf16 row-padded tensor bytes
  float* xs1 = (float*)alloc(ND * 4);
  float* xs2 = (float*)alloc(ND * 4);
  __hip_bfloat16* xb0 = (__hip_bfloat16*)alloc(ROWB);
  __hip_bfloat16* xb1 = (__hip_bfloat16*)alloc(ROWB);
  __hip_bfloat16* xb2 = (__hip_bfloat16*)alloc(ROWB);
  __hip_bfloat16* xb3 = (__hip_bfloat16*)alloc(ROWB);
  __hip_bfloat16* ag0 = (__hip_bfloat16*)alloc(ROWB);
  __hip_bfloat16* ag1 = (__hip_bfloat16*)alloc(ROWB);
  __hip_bfloat16* ag2 = (__hip_bfloat16*)alloc(ROWB);
  __hip_bfloat16* WT  = (__hip_bfloat16*)alloc(12 * 16384 * 2);
  int* cursor    = (int*)alloc((size_t)NB3 * 4);
  int* rowptr    = (int*)alloc((size_t)(NB3 + 1) * 4);
  int* blocksums = (int*)alloc(1024 * 4);
  int* dhist     = (int*)alloc(192 * 4);
  int* dcur      = (int*)alloc(192 * 4);
  int* wl        = (int*)alloc((size_t)NB3 * 4);
  int* csr_src   = (int*)alloc((size_t)(EDGES + 4 * NB3 + 16) * 4);

  hipLaunchKernelGGL(convw_kernel, dim3(12), dim3(256), 0, stream, Ws, Wk, WT);
  hipLaunchKernelGGL(x2b_kernel, dim3((int)(ND / 4 / 256)), dim3(256), 0, stream,
                     (const float4*)x, (uint2*)xb0, ND / 4);
  hipLaunchKernelGGL(zrow_kernel, dim3(1), dim3(256), 0, stream, xb0, xb1, xb2);
  hipMemsetAsync(cursor, 0, (size_t)NB3 * 4, stream);
  hipMemsetAsync(dhist, 0, 192 * 4, stream);
  int egrid  = (EDGES + 255) / 256;
  int sgridA = (NB3 + 255) / 256;
  hipLaunchKernelGGL(hist_kernel, dim3(egrid), dim3(256), 0, stream, ei, attr, cursor, EDGES);
  hipLaunchKernelGGL(scan_a_kernel, dim3(sgridA), dim3(256), 0, stream, cursor, rowptr, blocksums, NB3);
  hipLaunchKernelGGL(scan_b_kernel, dim3(1), dim3(256), 0, stream, blocksums, sgridA);
  hipLaunchKernelGGL(scan_c_kernel, dim3(sgridA), dim3(256), 0, stream, rowptr, cursor, blocksums, csr_src, NB3);
  hipLaunchKernelGGL(fill_kernel, dim3(egrid * NPART), dim3(256), 0, stream, ei, attr, cursor, csr_src, EDGES);
  hipLaunchKernelGGL(dhist_kernel, dim3(sgridA), dim3(256), 0, stream, rowptr, dhist);
  hipLaunchKernelGGL(dscan_kernel, dim3(1), dim3(64), 0, stream, dhist, dcur);
  hipLaunchKernelGGL(dfill_kernel, dim3(sgridA), dim3(256), 0, stream, rowptr, dcur, wl);

  int ggrid = (NODES + 63) / 64;   // 782
  auto glaunch = [&](int nwork, const __hip_bfloat16* s0, const __hip_bfloat16* s1,
                     const __hip_bfloat16* s2) {
    int blocks = (nwork * 16 + 255) / 256;
    hipLaunchKernelGGL(gather_kernel, dim3(blocks), dim3(256), 0, stream,
                       s0, s1, s2, rowptr, csr_src, wl, ag0, ag1, ag2, nwork);
  };

  // Layer 0
  glaunch(NODES, xb0, nullptr, nullptr);
  hipLaunchKernelGGL(lgemm_kernel, dim3(ggrid), dim3(256), 0, stream,
                     x, xb0, ag0, ag1, ag2, WT, bs + 0, bk + 0, eps + 0, xs1, xb1, 0);
  // Layer 1
  glaunch(2 * NODES, xb1, xb0, nullptr);
  hipLaunchKernelGGL(lgemm_kernel, dim3(ggrid), dim3(256), 0, stream,
                     xs1, xb1, ag0, ag1, ag2, WT, bs + 128, bk + 3 * 128, eps + 1, xs2, xb2, 1);
  // Layer 2
  glaunch(3 * NODES, xb2, xb1, xb0);
  hipLaunchKernelGGL(lgemm_kernel, dim3(ggrid), dim3(256), 0, stream,
                     xs2, xb2, ag0, ag1, ag2, WT, bs + 256, bk + 6 * 128, eps + 2, out, xb3, 2);
}

// Round 8
// 358.513 us; speedup vs baseline: 3.0278x; 3.0278x over previous
//
#include <hip/hip_runtime.h>
#include <hip/hip_bf16.h>

// DRew-GIN: N=50000, E=800000, D=128, L=3, NU=1.
// R8: R7 split arch (LDS-free gather + B-only-LDS GEMM) with contention-free
//     degree sort: LDS-privatized histogram -> flat matrix scan -> LDS-cursor fill.

#define NODES 50000
#define EDGES 800000
#define DIM   128
#define ND    ((long)NODES * DIM)
#define NB3   (3 * NODES)            // buckets: d*3 + (k-1)
#define NPART 8
#define PSIZE (NODES / NPART)
#define NROWP 50048                  // row-padded tensors (tail tile slack)
#define NBLKS ((NB3 + 255) / 256)    // 587
#define NCELL 192                    // 3 km1 * 64 size classes
#define SORTN (NCELL * NBLKS)        // 112704

typedef __attribute__((ext_vector_type(8))) short  bf16x8;
typedef __attribute__((ext_vector_type(4))) float  f32x4;

#define LDS_STRIDE 136   // bf16 elements; 272B rows

// ---------------------------------------------------------------------------
__global__ __launch_bounds__(256) void convw_kernel(
    const float* __restrict__ Ws, const float* __restrict__ Wk,
    __hip_bfloat16* __restrict__ WT) {
  int m = blockIdx.x;  // 0..11
  const float* src = (m < 3) ? (Ws + (long)m * 16384) : (Wk + (long)(m - 3) * 16384);
  __hip_bfloat16* dst = WT + (long)m * 16384;
  for (int idx = threadIdx.x; idx < 16384; idx += 256) {
    int k = idx >> 7, n = idx & 127;
    dst[n * 128 + k] = __float2bfloat16(src[idx]);
  }
}

__global__ __launch_bounds__(256) void x2b_kernel(
    const float4* __restrict__ xin, uint2* __restrict__ xbo, long n4) {
  long i = (long)blockIdx.x * 256 + threadIdx.x;
  if (i >= n4) return;
  float4 v = xin[i];
  union { __hip_bfloat16 h[4]; uint2 u; } pk;
  pk.h[0] = __float2bfloat16(v.x); pk.h[1] = __float2bfloat16(v.y);
  pk.h[2] = __float2bfloat16(v.z); pk.h[3] = __float2bfloat16(v.w);
  xbo[i] = pk.u;
}

__global__ __launch_bounds__(256) void zrow_kernel(
    __hip_bfloat16* __restrict__ xb0, __hip_bfloat16* __restrict__ xb1,
    __hip_bfloat16* __restrict__ xb2) {
  int i = threadIdx.x;
  if (i < DIM) {
    xb0[(long)NODES * DIM + i] = __float2bfloat16(0.f);
    xb1[(long)NODES * DIM + i] = __float2bfloat16(0.f);
    xb2[(long)NODES * DIM + i] = __float2bfloat16(0.f);
  }
}

// ---------------------------------------------------------------------------
// CSR build (pad-to-4).
__global__ __launch_bounds__(256) void hist_kernel(
    const int* __restrict__ ei, const int* __restrict__ attr,
    int* __restrict__ counts, int E) {
  int e = blockIdx.x * 256 + threadIdx.x;
  if (e >= E) return;
  atomicAdd(&counts[ei[E + e] * 3 + (attr[e] - 1)], 1);
}

__global__ __launch_bounds__(256) void scan_a_kernel(
    const int* __restrict__ counts, int* __restrict__ partial,
    int* __restrict__ blocksums, int n) {
  __shared__ int tmp[256];
  int gid = blockIdx.x * 256 + threadIdx.x;
  int v = (gid < n) ? ((counts[gid] + 3) & ~3) : 0;
  tmp[threadIdx.x] = v;
  __syncthreads();
  for (int off = 1; off < 256; off <<= 1) {
    int t = (threadIdx.x >= off) ? tmp[threadIdx.x - off] : 0;
    __syncthreads();
    tmp[threadIdx.x] += t;
    __syncthreads();
  }
  if (gid < n) partial[gid] = tmp[threadIdx.x] - v;
  if (threadIdx.x == 255) blocksums[blockIdx.x] = tmp[255];
}

__global__ __launch_bounds__(256) void scan_b_kernel(int* __restrict__ bs, int nb) {
  __shared__ int tmp[256];
  __shared__ int carry;
  if (threadIdx.x == 0) carry = 0;
  __syncthreads();
  for (int base = 0; base < nb; base += 256) {
    int gid = base + threadIdx.x;
    int v = (gid < nb) ? bs[gid] : 0;
    tmp[threadIdx.x] = v;
    __syncthreads();
    for (int off = 1; off < 256; off <<= 1) {
      int t = (threadIdx.x >= off) ? tmp[threadIdx.x - off] : 0;
      __syncthreads();
      tmp[threadIdx.x] += t;
      __syncthreads();
    }
    if (gid < nb) bs[gid] = tmp[threadIdx.x] - v + carry;
    __syncthreads();
    if (threadIdx.x == 0) carry += tmp[255];
    __syncthreads();
  }
}

__global__ __launch_bounds__(256) void scan_c_kernel(
    int* __restrict__ rowptr, int* __restrict__ cursor,
    const int* __restrict__ bs, int* __restrict__ csr, int n) {
  int gid = blockIdx.x * 256 + threadIdx.x;
  if (gid >= n) return;
  int cnt = cursor[gid];
  int pcnt = (cnt + 3) & ~3;
  int val = rowptr[gid] + bs[blockIdx.x];
  rowptr[gid] = val;
  cursor[gid] = val;
  for (int i = cnt; i < pcnt; ++i) csr[val + i] = NODES;
  if (gid == n - 1) rowptr[n] = val + pcnt;
}

__global__ __launch_bounds__(256) void fill_kernel(
    const int* __restrict__ ei, const int* __restrict__ attr,
    int* __restrict__ cursor, int* __restrict__ csr_src, int E) {
  int p = blockIdx.x & (NPART - 1);
  int chunk = blockIdx.x >> 3;
  int e = chunk * 256 + threadIdx.x;
  if (e >= E) return;
  int d = ei[E + e];
  int lo = p * PSIZE;
  if (d < lo || d >= lo + PSIZE) return;
  int pos = atomicAdd(&cursor[d * 3 + (attr[e] - 1)], 1);
  csr_src[pos] = ei[e];
}

// ---------------------------------------------------------------------------
// Degree sort, contention-free.
// cell = km1*64 + (63 - min(pcnt/4,63))  -> scan order = km1-major, big-first.
__device__ __forceinline__ int bucket_cell(const int* rowptr, int b) {
  int c = (rowptr[b + 1] - rowptr[b]) >> 2;
  if (c > 63) c = 63;
  int km1 = b - (b / 3) * 3;
  return km1 * 64 + (63 - c);
}

__global__ __launch_bounds__(256) void bhist_kernel(
    const int* __restrict__ rowptr, int* __restrict__ G) {
  __shared__ int h[NCELL];
  if (threadIdx.x < NCELL) h[threadIdx.x] = 0;
  __syncthreads();
  int b = blockIdx.x * 256 + threadIdx.x;
  if (b < NB3) atomicAdd(&h[bucket_cell(rowptr, b)], 1);
  __syncthreads();
  if (threadIdx.x < NCELL) G[threadIdx.x * NBLKS + blockIdx.x] = h[threadIdx.x];
}

// Generic flat exclusive scan (pass 1): in -> partial (exclusive within block).
__global__ __launch_bounds__(256) void fscan_a_kernel(
    const int* __restrict__ in, int* __restrict__ partial,
    int* __restrict__ blocksums, int n) {
  __shared__ int tmp[256];
  int gid = blockIdx.x * 256 + threadIdx.x;
  int v = (gid < n) ? in[gid] : 0;
  tmp[threadIdx.x] = v;
  __syncthreads();
  for (int off = 1; off < 256; off <<= 1) {
    int t = (threadIdx.x >= off) ? tmp[threadIdx.x - off] : 0;
    __syncthreads();
    tmp[threadIdx.x] += t;
    __syncthreads();
  }
  if (gid < n) partial[gid] = tmp[threadIdx.x] - v;
  if (threadIdx.x == 255) blocksums[blockIdx.x] = tmp[255];
}

__global__ __launch_bounds__(256) void fscan_c_kernel(
    int* __restrict__ partial, const int* __restrict__ bs, int n) {
  int gid = blockIdx.x * 256 + threadIdx.x;
  if (gid >= n) return;
  partial[gid] += bs[blockIdx.x];
}

__global__ __launch_bounds__(256) void bfill_kernel(
    const int* __restrict__ rowptr, const int* __restrict__ Gscan,
    int* __restrict__ wl) {
  __shared__ int base[NCELL];
  if (threadIdx.x < NCELL)
    base[threadIdx.x] = Gscan[threadIdx.x * NBLKS + blockIdx.x];
  __syncthreads();
  int b = blockIdx.x * 256 + threadIdx.x;
  if (b >= NB3) return;
  int pos = atomicAdd(&base[bucket_cell(rowptr, b)], 1);  // LDS atomic
  wl[pos] = b;
}

// ---------------------------------------------------------------------------
// Gather: one 16-lane group per worklist bucket. No LDS. 4-deep uint4 pipeline.
__global__ __launch_bounds__(256, 6) void gather_kernel(
    const __hip_bfloat16* __restrict__ s0,
    const __hip_bfloat16* __restrict__ s1,
    const __hip_bfloat16* __restrict__ s2,
    const int* __restrict__ rowptr, const int* __restrict__ csr,
    const int* __restrict__ wl,
    __hip_bfloat16* __restrict__ ag0, __hip_bfloat16* __restrict__ ag1,
    __hip_bfloat16* __restrict__ ag2, int nwork) {
  int group = (blockIdx.x * 256 + threadIdx.x) >> 4;
  int lane16 = threadIdx.x & 15;
  if (group >= nwork) return;
  int b = wl[group];
  int d = b / 3;
  int km1 = b - d * 3;
  const __hip_bfloat16* xb = (km1 == 0) ? s0 : ((km1 == 1) ? s1 : s2);
  __hip_bfloat16* ag = (km1 == 0) ? ag0 : ((km1 == 1) ? ag1 : ag2);
  int beg = rowptr[b], end = rowptr[b + 1];   // (end-beg)%4 == 0
  float a0 = 0.f, a1 = 0.f, a2 = 0.f, a3 = 0.f,
        a4 = 0.f, a5 = 0.f, a6 = 0.f, a7 = 0.f;
  for (int base = beg; base < end; base += 16) {
    int idxv = csr[base + lane16];            // slack-allocated
    int cnt = end - base; if (cnt > 16) cnt = 16;
    for (int j = 0; j < cnt; j += 4) {
      int q0 = __shfl(idxv, j + 0, 16);
      int q1 = __shfl(idxv, j + 1, 16);
      int q2 = __shfl(idxv, j + 2, 16);
      int q3 = __shfl(idxv, j + 3, 16);
      uint4 v0 = *(const uint4*)(xb + (long)q0 * DIM + lane16 * 8);
      uint4 v1 = *(const uint4*)(xb + (long)q1 * DIM + lane16 * 8);
      uint4 v2 = *(const uint4*)(xb + (long)q2 * DIM + lane16 * 8);
      uint4 v3 = *(const uint4*)(xb + (long)q3 * DIM + lane16 * 8);
      a0 += __uint_as_float(v0.x << 16) + __uint_as_float(v1.x << 16)
          + __uint_as_float(v2.x << 16) + __uint_as_float(v3.x << 16);
      a1 += __uint_as_float(v0.x & 0xffff0000u) + __uint_as_float(v1.x & 0xffff0000u)
          + __uint_as_float(v2.x & 0xffff0000u) + __uint_as_float(v3.x & 0xffff0000u);
      a2 += __uint_as_float(v0.y << 16) + __uint_as_float(v1.y << 16)
          + __uint_as_float(v2.y << 16) + __uint_as_float(v3.y << 16);
      a3 += __uint_as_float(v0.y & 0xffff0000u) + __uint_as_float(v1.y & 0xffff0000u)
          + __uint_as_float(v2.y & 0xffff0000u) + __uint_as_float(v3.y & 0xffff0000u);
      a4 += __uint_as_float(v0.z << 16) + __uint_as_float(v1.z << 16)
          + __uint_as_float(v2.z << 16) + __uint_as_float(v3.z << 16);
      a5 += __uint_as_float(v0.z & 0xffff0000u) + __uint_as_float(v1.z & 0xffff0000u)
          + __uint_as_float(v2.z & 0xffff0000u) + __uint_as_float(v3.z & 0xffff0000u);
      a6 += __uint_as_float(v0.w << 16) + __uint_as_float(v1.w << 16)
          + __uint_as_float(v2.w << 16) + __uint_as_float(v3.w << 16);
      a7 += __uint_as_float(v0.w & 0xffff0000u) + __uint_as_float(v1.w & 0xffff0000u)
          + __uint_as_float(v2.w & 0xffff0000u) + __uint_as_float(v3.w & 0xffff0000u);
    }
  }
  union { __hip_bfloat16 h[8]; uint4 u; } pk;
  pk.h[0] = __float2bfloat16(a0); pk.h[1] = __float2bfloat16(a1);
  pk.h[2] = __float2bfloat16(a2); pk.h[3] = __float2bfloat16(a3);
  pk.h[4] = __float2bfloat16(a4); pk.h[5] = __float2bfloat16(a5);
  pk.h[6] = __float2bfloat16(a6); pk.h[7] = __float2bfloat16(a7);
  *(uint4*)(ag + (long)d * DIM + lane16 * 8) = pk.u;
}

// ---------------------------------------------------------------------------
// Layer GEMM: A-frags direct from global bf16; only B staged in LDS.
__global__ __launch_bounds__(256, 4) void lgemm_kernel(
    const float* __restrict__ xt,
    const __hip_bfloat16* __restrict__ xbSelf,
    const __hip_bfloat16* __restrict__ ag0,
    const __hip_bfloat16* __restrict__ ag1,
    const __hip_bfloat16* __restrict__ ag2,
    const __hip_bfloat16* __restrict__ WT,
    const float* __restrict__ bs_t,
    const float* __restrict__ bk_t,
    const float* __restrict__ epsp,
    float* __restrict__ xn,
    __hip_bfloat16* __restrict__ xnb,
    int t) {
  __shared__ __hip_bfloat16 b_lds[128 * LDS_STRIDE];  // 34816 B

  int tid = threadIdx.x;
  long row0 = (long)blockIdx.x * 64;
  int wave = tid >> 6, lane = tid & 63;
  int l15 = lane & 15, q = lane >> 4;
  long arow = row0 + wave * 16 + l15;

  const __hip_bfloat16* Asrc[4] = {xbSelf, ag0, ag1, ag2};
  f32x4 out[8];

  for (int p = 0; p <= t + 1; ++p) {
    if (p > 0) __syncthreads();
    const __hip_bfloat16* Am = Asrc[p];
    uint4 af[4];
#pragma unroll
    for (int k0i = 0; k0i < 4; ++k0i)
      af[k0i] = *(const uint4*)(Am + arow * DIM + k0i * 32 + 8 * q);
    const __hip_bfloat16* W = (p == 0) ? (WT + (long)t * 16384)
                                       : (WT + (long)(3 + t * 3 + (p - 1)) * 16384);
    {
      const uint4* bq = (const uint4*)W;
#pragma unroll
      for (int i = 0; i < 8; ++i) {
        int idx = tid + 256 * i;
        int n = idx >> 4, k8 = idx & 15;
        uint4 v = bq[idx];
        *(uint4*)(b_lds + n * LDS_STRIDE + k8 * 8) = v;
      }
    }
    __syncthreads();

    f32x4 acc[8] = {};
#pragma unroll
    for (int k0i = 0; k0i < 4; ++k0i) {
      bf16x8 a = __builtin_bit_cast(bf16x8, af[k0i]);
#pragma unroll
      for (int j = 0; j < 8; ++j) {
        bf16x8 bfr = *(const bf16x8*)(b_lds + (16 * j + l15) * LDS_STRIDE + k0i * 32 + 8 * q);
        acc[j] = __builtin_amdgcn_mfma_f32_16x16x32_bf16(a, bfr, acc[j], 0, 0, 0);
      }
    }
    if (p == 0) {
      float sc = 1.0f + *epsp;
#pragma unroll
      for (int j = 0; j < 8; ++j) {
        float b = bs_t[16 * j + l15];
#pragma unroll
        for (int r = 0; r < 4; ++r) out[j][r] = sc * fmaxf(acc[j][r] + b, 0.f);
      }
    } else {
      const float* bb = bk_t + (p - 1) * 128;
#pragma unroll
      for (int j = 0; j < 8; ++j) {
        float b = bb[16 * j + l15];
#pragma unroll
        for (int r = 0; r < 4; ++r) out[j][r] += fmaxf(acc[j][r] + b, 0.f);
      }
    }
  }

  long rbase = row0 + wave * 16 + q * 4;
#pragma unroll
  for (int j = 0; j < 8; ++j) {
    int col = 16 * j + l15;
#pragma unroll
    for (int r = 0; r < 4; ++r) {
      long grow = rbase + r;
      if (grow < NODES) {
        float v = xt[grow * DIM + col] + fmaxf(out[j][r], 0.f);
        xn[grow * DIM + col] = v;
        xnb[grow * DIM + col] = __float2bfloat16(v);
      }
    }
  }
}

// ---------------------------------------------------------------------------
extern "C" void kernel_launch(void* const* d_in, const int* in_sizes, int n_in,
                              void* d_out, int out_size, void* d_ws, size_t ws_size,
                              hipStream_t stream) {
  const float* x    = (const float*)d_in[0];
  const int*   ei   = (const int*)d_in[1];
  const int*   attr = (const int*)d_in[2];
  const float* Ws   = (const float*)d_in[3];
  const float* bs   = (const float*)d_in[4];
  const float* Wk   = (const float*)d_in[5];
  const float* bk   = (const float*)d_in[6];
  const float* eps  = (const float*)d_in[7];
  float* out = (float*)d_out;

  char* ws = (char*)d_ws;
  size_t off = 0;
  auto alloc = [&](size_t bytes) { char* p = ws + off; off += (bytes + 255) & ~(size_t)255; return p; };
  const size_t ROWB = (size_t)NROWP * DIM * 2;
  float* xs1 = (float*)alloc(ND * 4);
  float* xs2 = (float*)alloc(ND * 4);
  __hip_bfloat16* xb0 = (__hip_bfloat16*)alloc(ROWB);
  __hip_bfloat16* xb1 = (__hip_bfloat16*)alloc(ROWB);
  __hip_bfloat16* xb2 = (__hip_bfloat16*)alloc(ROWB);
  __hip_bfloat16* xb3 = (__hip_bfloat16*)alloc(ROWB);
  __hip_bfloat16* ag0 = (__hip_bfloat16*)alloc(ROWB);
  __hip_bfloat16* ag1 = (__hip_bfloat16*)alloc(ROWB);
  __hip_bfloat16* ag2 = (__hip_bfloat16*)alloc(ROWB);
  __hip_bfloat16* WT  = (__hip_bfloat16*)alloc(12 * 16384 * 2);
  int* cursor    = (int*)alloc((size_t)NB3 * 4);
  int* rowptr    = (int*)alloc((size_t)(NB3 + 1) * 4);
  int* blocksums = (int*)alloc(1024 * 4);
  int* G         = (int*)alloc((size_t)SORTN * 4);
  int* bsum2     = (int*)alloc(1024 * 4);
  int* wl        = (int*)alloc((size_t)NB3 * 4);
  int* csr_src   = (int*)alloc((size_t)(EDGES + 4 * NB3 + 16) * 4);

  hipLaunchKernelGGL(convw_kernel, dim3(12), dim3(256), 0, stream, Ws, Wk, WT);
  hipLaunchKernelGGL(x2b_kernel, dim3((int)(ND / 4 / 256)), dim3(256), 0, stream,
                     (const float4*)x, (uint2*)xb0, ND / 4);
  hipLaunchKernelGGL(zrow_kernel, dim3(1), dim3(256), 0, stream, xb0, xb1, xb2);
  hipMemsetAsync(cursor, 0, (size_t)NB3 * 4, stream);
  int egrid  = (EDGES + 255) / 256;
  int sgridA = (NB3 + 255) / 256;          // 587 == NBLKS
  hipLaunchKernelGGL(hist_kernel, dim3(egrid), dim3(256), 0, stream, ei, attr, cursor, EDGES);
  hipLaunchKernelGGL(scan_a_kernel, dim3(sgridA), dim3(256), 0, stream, cursor, rowptr, blocksums, NB3);
  hipLaunchKernelGGL(scan_b_kernel, dim3(1), dim3(256), 0, stream, blocksums, sgridA);
  hipLaunchKernelGGL(scan_c_kernel, dim3(sgridA), dim3(256), 0, stream, rowptr, cursor, blocksums, csr_src, NB3);
  hipLaunchKernelGGL(fill_kernel, dim3(egrid * NPART), dim3(256), 0, stream, ei, attr, cursor, csr_src, EDGES);

  // Degree sort (contention-free).
  int fgrid = (SORTN + 255) / 256;         // 441
  hipLaunchKernelGGL(bhist_kernel, dim3(NBLKS), dim3(256), 0, stream, rowptr, G);
  hipLaunchKernelGGL(fscan_a_kernel, dim3(fgrid), dim3(256), 0, stream, G, G, bsum2, SORTN);
  hipLaunchKernelGGL(scan_b_kernel, dim3(1), dim3(256), 0, stream, bsum2, fgrid);
  hipLaunchKernelGGL(fscan_c_kernel, dim3(fgrid), dim3(256), 0, stream, G, bsum2, SORTN);
  hipLaunchKernelGGL(bfill_kernel, dim3(NBLKS), dim3(256), 0, stream, rowptr, G, wl);

  int ggrid = (NODES + 63) / 64;
  auto glaunch = [&](int nwork, const __hip_bfloat16* s0, const __hip_bfloat16* s1,
                     const __hip_bfloat16* s2) {
    int blocks = (nwork * 16 + 255) / 256;
    hipLaunchKernelGGL(gather_kernel, dim3(blocks), dim3(256), 0, stream,
                       s0, s1, s2, rowptr, csr_src, wl, ag0, ag1, ag2, nwork);
  };

  // Layer 0
  glaunch(NODES, xb0, nullptr, nullptr);
  hipLaunchKernelGGL(lgemm_kernel, dim3(ggrid), dim3(256), 0, stream,
                     x, xb0, ag0, ag1, ag2, WT, bs + 0, bk + 0, eps + 0, xs1, xb1, 0);
  // Layer 1
  glaunch(2 * NODES, xb1, xb0, nullptr);
  hipLaunchKernelGGL(lgemm_kernel, dim3(ggrid), dim3(256), 0, stream,
                     xs1, xb1, ag0, ag1, ag2, WT, bs + 128, bk + 3 * 128, eps + 1, xs2, xb2, 1);
  // Layer 2
  glaunch(3 * NODES, xb2, xb1, xb0);
  hipLaunchKernelGGL(lgemm_kernel, dim3(ggrid), dim3(256), 0, stream,
                     xs2, xb2, ag0, ag1, ag2, WT, bs + 256, bk + 6 * 128, eps + 2, out, xb3, 2);
}

// Round 9
// 336.569 us; speedup vs baseline: 3.2252x; 1.0652x over previous
//
#include <hip/hip_runtime.h>
#include <hip/hip_bf16.h>

// DRew-GIN: N=50000, E=800000, D=128, L=3, NU=1.
// R9: bf16-only node state (no f32 masters), fused init kernel, fused
//     scan_c+bhist, fscan_c folded into bfill. 15 launches total.

#define NODES 50000
#define EDGES 800000
#define DIM   128
#define ND    ((long)NODES * DIM)
#define NB3   (3 * NODES)            // buckets: d*3 + (k-1)
#define NPART 8
#define PSIZE (NODES / NPART)
#define NROWP 50048                  // row-padded tensors (tail tile slack)
#define NBLKS ((NB3 + 255) / 256)    // 587
#define NCELL 192                    // 3 km1 * 64 size classes
#define SORTN (NCELL * NBLKS)        // 112704

typedef __attribute__((ext_vector_type(8))) short  bf16x8;
typedef __attribute__((ext_vector_type(4))) float  f32x4;

#define LDS_STRIDE 136   // bf16 elements; 272B rows

// ---------------------------------------------------------------------------
// init: x->bf16 shadow, weight conversion, dummy-row zero, cursor zero.
__global__ __launch_bounds__(256) void init_kernel(
    const float* __restrict__ x, const float* __restrict__ Ws,
    const float* __restrict__ Wk, __hip_bfloat16* __restrict__ xb0,
    __hip_bfloat16* __restrict__ xb1, __hip_bfloat16* __restrict__ xb2,
    __hip_bfloat16* __restrict__ WT, int* __restrict__ cursor) {
  int b = blockIdx.x, tid = threadIdx.x;
  // x -> bf16 shadow (all blocks; ND/4 = 1.6M float4)
  long i = (long)b * 256 + tid;
  if (i < ND / 4) {
    float4 v = ((const float4*)x)[i];
    union { __hip_bfloat16 h[4]; uint2 u; } pk;
    pk.h[0] = __float2bfloat16(v.x); pk.h[1] = __float2bfloat16(v.y);
    pk.h[2] = __float2bfloat16(v.z); pk.h[3] = __float2bfloat16(v.w);
    ((uint2*)xb0)[i] = pk.u;
  }
  // weight conversion: blocks 0..11
  if (b < 12) {
    const float* src = (b < 3) ? (Ws + (long)b * 16384) : (Wk + (long)(b - 3) * 16384);
    __hip_bfloat16* dst = WT + (long)b * 16384;
    for (int idx = tid; idx < 16384; idx += 256) {
      int k = idx >> 7, n = idx & 127;
      dst[n * 128 + k] = __float2bfloat16(src[idx]);
    }
  }
  // cursor zero: blocks 12..598
  if (b >= 12 && b < 12 + NBLKS) {
    int g = (b - 12) * 256 + tid;
    if (g < NB3) cursor[g] = 0;
  }
  // dummy zero rows: block 599
  if (b == 599 && tid < DIM) {
    xb0[(long)NODES * DIM + tid] = __float2bfloat16(0.f);
    xb1[(long)NODES * DIM + tid] = __float2bfloat16(0.f);
    xb2[(long)NODES * DIM + tid] = __float2bfloat16(0.f);
  }
}

// ---------------------------------------------------------------------------
// CSR build (pad-to-4).
__global__ __launch_bounds__(256) void hist_kernel(
    const int* __restrict__ ei, const int* __restrict__ attr,
    int* __restrict__ counts, int E) {
  int e = blockIdx.x * 256 + threadIdx.x;
  if (e >= E) return;
  atomicAdd(&counts[ei[E + e] * 3 + (attr[e] - 1)], 1);
}

__global__ __launch_bounds__(256) void scan_a_kernel(
    const int* __restrict__ counts, int* __restrict__ partial,
    int* __restrict__ blocksums, int n) {
  __shared__ int tmp[256];
  int gid = blockIdx.x * 256 + threadIdx.x;
  int v = (gid < n) ? ((counts[gid] + 3) & ~3) : 0;
  tmp[threadIdx.x] = v;
  __syncthreads();
  for (int off = 1; off < 256; off <<= 1) {
    int t = (threadIdx.x >= off) ? tmp[threadIdx.x - off] : 0;
    __syncthreads();
    tmp[threadIdx.x] += t;
    __syncthreads();
  }
  if (gid < n) partial[gid] = tmp[threadIdx.x] - v;
  if (threadIdx.x == 255) blocksums[blockIdx.x] = tmp[255];
}

__global__ __launch_bounds__(256) void scan_b_kernel(int* __restrict__ bs, int nb) {
  __shared__ int tmp[256];
  __shared__ int carry;
  if (threadIdx.x == 0) carry = 0;
  __syncthreads();
  for (int base = 0; base < nb; base += 256) {
    int gid = base + threadIdx.x;
    int v = (gid < nb) ? bs[gid] : 0;
    tmp[threadIdx.x] = v;
    __syncthreads();
    for (int off = 1; off < 256; off <<= 1) {
      int t = (threadIdx.x >= off) ? tmp[threadIdx.x - off] : 0;
      __syncthreads();
      tmp[threadIdx.x] += t;
      __syncthreads();
    }
    if (gid < nb) bs[gid] = tmp[threadIdx.x] - v + carry;
    __syncthreads();
    if (threadIdx.x == 0) carry += tmp[255];
    __syncthreads();
  }
}

// scan_c + sort histogram fused. cell order: km1-major, big-first.
__global__ __launch_bounds__(256) void scanc_bhist_kernel(
    int* __restrict__ rowptr, int* __restrict__ cursor,
    const int* __restrict__ bs, int* __restrict__ csr,
    int* __restrict__ G, int n) {
  __shared__ int h[NCELL];
  if (threadIdx.x < NCELL) h[threadIdx.x] = 0;
  __syncthreads();
  int gid = blockIdx.x * 256 + threadIdx.x;
  if (gid < n) {
    int cnt = cursor[gid];
    int pcnt = (cnt + 3) & ~3;
    int val = rowptr[gid] + bs[blockIdx.x];
    rowptr[gid] = val;
    cursor[gid] = val;
    for (int i = cnt; i < pcnt; ++i) csr[val + i] = NODES;
    if (gid == n - 1) rowptr[n] = val + pcnt;
    int c = pcnt >> 2; if (c > 63) c = 63;
    int km1 = gid - (gid / 3) * 3;
    atomicAdd(&h[km1 * 64 + (63 - c)], 1);
  }
  __syncthreads();
  if (threadIdx.x < NCELL) G[threadIdx.x * NBLKS + blockIdx.x] = h[threadIdx.x];
}

__global__ __launch_bounds__(256) void fill_kernel(
    const int* __restrict__ ei, const int* __restrict__ attr,
    int* __restrict__ cursor, int* __restrict__ csr_src, int E) {
  int p = blockIdx.x & (NPART - 1);
  int chunk = blockIdx.x >> 3;
  int e = chunk * 256 + threadIdx.x;
  if (e >= E) return;
  int d = ei[E + e];
  int lo = p * PSIZE;
  if (d < lo || d >= lo + PSIZE) return;
  int pos = atomicAdd(&cursor[d * 3 + (attr[e] - 1)], 1);
  csr_src[pos] = ei[e];
}

// Flat exclusive scan pass 1 (in-place ok: in==partial).
__global__ __launch_bounds__(256) void fscan_a_kernel(
    const int* __restrict__ in, int* __restrict__ partial,
    int* __restrict__ blocksums, int n) {
  __shared__ int tmp[256];
  int gid = blockIdx.x * 256 + threadIdx.x;
  int v = (gid < n) ? in[gid] : 0;
  tmp[threadIdx.x] = v;
  __syncthreads();
  for (int off = 1; off < 256; off <<= 1) {
    int t = (threadIdx.x >= off) ? tmp[threadIdx.x - off] : 0;
    __syncthreads();
    tmp[threadIdx.x] += t;
    __syncthreads();
  }
  if (gid < n) partial[gid] = tmp[threadIdx.x] - v;
  if (threadIdx.x == 255) blocksums[blockIdx.x] = tmp[255];
}

// bfill with fscan_c folded in: base = Gpartial + bsum2[Gidx>>8].
__global__ __launch_bounds__(256) void bfill_kernel(
    const int* __restrict__ rowptr, const int* __restrict__ G,
    const int* __restrict__ bsum2, int* __restrict__ wl) {
  __shared__ int base[NCELL];
  if (threadIdx.x < NCELL) {
    int gidx = threadIdx.x * NBLKS + blockIdx.x;
    base[threadIdx.x] = G[gidx] + bsum2[gidx >> 8];
  }
  __syncthreads();
  int b = blockIdx.x * 256 + threadIdx.x;
  if (b >= NB3) return;
  int pcnt = rowptr[b + 1] - rowptr[b];
  int c = pcnt >> 2; if (c > 63) c = 63;
  int km1 = b - (b / 3) * 3;
  int pos = atomicAdd(&base[km1 * 64 + (63 - c)], 1);  // LDS atomic
  wl[pos] = b;
}

// ---------------------------------------------------------------------------
// Gather: one 16-lane group per worklist bucket. No LDS. 4-deep uint4 pipeline.
__global__ __launch_bounds__(256, 6) void gather_kernel(
    const __hip_bfloat16* __restrict__ s0,
    const __hip_bfloat16* __restrict__ s1,
    const __hip_bfloat16* __restrict__ s2,
    const int* __restrict__ rowptr, const int* __restrict__ csr,
    const int* __restrict__ wl,
    __hip_bfloat16* __restrict__ ag0, __hip_bfloat16* __restrict__ ag1,
    __hip_bfloat16* __restrict__ ag2, int nwork) {
  int group = (blockIdx.x * 256 + threadIdx.x) >> 4;
  int lane16 = threadIdx.x & 15;
  if (group >= nwork) return;
  int b = wl[group];
  int d = b / 3;
  int km1 = b - d * 3;
  const __hip_bfloat16* xb = (km1 == 0) ? s0 : ((km1 == 1) ? s1 : s2);
  __hip_bfloat16* ag = (km1 == 0) ? ag0 : ((km1 == 1) ? ag1 : ag2);
  int beg = rowptr[b], end = rowptr[b + 1];   // (end-beg)%4 == 0
  float a0 = 0.f, a1 = 0.f, a2 = 0.f, a3 = 0.f,
        a4 = 0.f, a5 = 0.f, a6 = 0.f, a7 = 0.f;
  for (int base = beg; base < end; base += 16) {
    int idxv = csr[base + lane16];            // slack-allocated
    int cnt = end - base; if (cnt > 16) cnt = 16;
    for (int j = 0; j < cnt; j += 4) {
      int q0 = __shfl(idxv, j + 0, 16);
      int q1 = __shfl(idxv, j + 1, 16);
      int q2 = __shfl(idxv, j + 2, 16);
      int q3 = __shfl(idxv, j + 3, 16);
      uint4 v0 = *(const uint4*)(xb + (long)q0 * DIM + lane16 * 8);
      uint4 v1 = *(const uint4*)(xb + (long)q1 * DIM + lane16 * 8);
      uint4 v2 = *(const uint4*)(xb + (long)q2 * DIM + lane16 * 8);
      uint4 v3 = *(const uint4*)(xb + (long)q3 * DIM + lane16 * 8);
      a0 += __uint_as_float(v0.x << 16) + __uint_as_float(v1.x << 16)
          + __uint_as_float(v2.x << 16) + __uint_as_float(v3.x << 16);
      a1 += __uint_as_float(v0.x & 0xffff0000u) + __uint_as_float(v1.x & 0xffff0000u)
          + __uint_as_float(v2.x & 0xffff0000u) + __uint_as_float(v3.x & 0xffff0000u);
      a2 += __uint_as_float(v0.y << 16) + __uint_as_float(v1.y << 16)
          + __uint_as_float(v2.y << 16) + __uint_as_float(v3.y << 16);
      a3 += __uint_as_float(v0.y & 0xffff0000u) + __uint_as_float(v1.y & 0xffff0000u)
          + __uint_as_float(v2.y & 0xffff0000u) + __uint_as_float(v3.y & 0xffff0000u);
      a4 += __uint_as_float(v0.z << 16) + __uint_as_float(v1.z << 16)
          + __uint_as_float(v2.z << 16) + __uint_as_float(v3.z << 16);
      a5 += __uint_as_float(v0.z & 0xffff0000u) + __uint_as_float(v1.z & 0xffff0000u)
          + __uint_as_float(v2.z & 0xffff0000u) + __uint_as_float(v3.z & 0xffff0000u);
      a6 += __uint_as_float(v0.w << 16) + __uint_as_float(v1.w << 16)
          + __uint_as_float(v2.w << 16) + __uint_as_float(v3.w << 16);
      a7 += __uint_as_float(v0.w & 0xffff0000u) + __uint_as_float(v1.w & 0xffff0000u)
          + __uint_as_float(v2.w & 0xffff0000u) + __uint_as_float(v3.w & 0xffff0000u);
    }
  }
  union { __hip_bfloat16 h[8]; uint4 u; } pk;
  pk.h[0] = __float2bfloat16(a0); pk.h[1] = __float2bfloat16(a1);
  pk.h[2] = __float2bfloat16(a2); pk.h[3] = __float2bfloat16(a3);
  pk.h[4] = __float2bfloat16(a4); pk.h[5] = __float2bfloat16(a5);
  pk.h[6] = __float2bfloat16(a6); pk.h[7] = __float2bfloat16(a7);
  *(uint4*)(ag + (long)d * DIM + lane16 * 8) = pk.u;
}

// ---------------------------------------------------------------------------
// Layer GEMM: bf16 node state. Residual read from xbSelf (L1-hot).
// Layers 0/1: write bf16 shadow xnb. Layer 2 (xn != null): write f32 xn only.
__global__ __launch_bounds__(256, 4) void lgemm_kernel(
    const __hip_bfloat16* __restrict__ xbSelf,
    const __hip_bfloat16* __restrict__ ag0,
    const __hip_bfloat16* __restrict__ ag1,
    const __hip_bfloat16* __restrict__ ag2,
    const __hip_bfloat16* __restrict__ WT,
    const float* __restrict__ bs_t,
    const float* __restrict__ bk_t,
    const float* __restrict__ epsp,
    __hip_bfloat16* __restrict__ xnb,   // bf16 out (layers 0/1)
    float* __restrict__ xn,             // f32 out (final layer) or null
    int t) {
  __shared__ __hip_bfloat16 b_lds[128 * LDS_STRIDE];  // 34816 B

  int tid = threadIdx.x;
  long row0 = (long)blockIdx.x * 64;
  int wave = tid >> 6, lane = tid & 63;
  int l15 = lane & 15, q = lane >> 4;
  long arow = row0 + wave * 16 + l15;

  const __hip_bfloat16* Asrc[4] = {xbSelf, ag0, ag1, ag2};
  f32x4 out[8];

  for (int p = 0; p <= t + 1; ++p) {
    if (p > 0) __syncthreads();
    const __hip_bfloat16* Am = Asrc[p];
    uint4 af[4];
#pragma unroll
    for (int k0i = 0; k0i < 4; ++k0i)
      af[k0i] = *(const uint4*)(Am + arow * DIM + k0i * 32 + 8 * q);
    const __hip_bfloat16* W = (p == 0) ? (WT + (long)t * 16384)
                                       : (WT + (long)(3 + t * 3 + (p - 1)) * 16384);
    {
      const uint4* bq = (const uint4*)W;
#pragma unroll
      for (int i = 0; i < 8; ++i) {
        int idx = tid + 256 * i;
        int n = idx >> 4, k8 = idx & 15;
        uint4 v = bq[idx];
        *(uint4*)(b_lds + n * LDS_STRIDE + k8 * 8) = v;
      }
    }
    __syncthreads();

    f32x4 acc[8] = {};
#pragma unroll
    for (int k0i = 0; k0i < 4; ++k0i) {
      bf16x8 a = __builtin_bit_cast(bf16x8, af[k0i]);
#pragma unroll
      for (int j = 0; j < 8; ++j) {
        bf16x8 bfr = *(const bf16x8*)(b_lds + (16 * j + l15) * LDS_STRIDE + k0i * 32 + 8 * q);
        acc[j] = __builtin_amdgcn_mfma_f32_16x16x32_bf16(a, bfr, acc[j], 0, 0, 0);
      }
    }
    if (p == 0) {
      float sc = 1.0f + *epsp;
#pragma unroll
      for (int j = 0; j < 8; ++j) {
        float b = bs_t[16 * j + l15];
#pragma unroll
        for (int r = 0; r < 4; ++r) out[j][r] = sc * fmaxf(acc[j][r] + b, 0.f);
      }
    } else {
      const float* bb = bk_t + (p - 1) * 128;
#pragma unroll
      for (int j = 0; j < 8; ++j) {
        float b = bb[16 * j + l15];
#pragma unroll
        for (int r = 0; r < 4; ++r) out[j][r] += fmaxf(acc[j][r] + b, 0.f);
      }
    }
  }

  // Epilogue: v = bf16_residual + relu(out).
  long rbase = row0 + wave * 16 + q * 4;
  bool fin = (xn != nullptr);
#pragma unroll
  for (int j = 0; j < 8; ++j) {
    int col = 16 * j + l15;
#pragma unroll
    for (int r = 0; r < 4; ++r) {
      long grow = rbase + r;
      if (grow < NODES) {
        float res = __bfloat162float(xbSelf[grow * DIM + col]);
        float v = res + fmaxf(out[j][r], 0.f);
        if (fin) xn[grow * DIM + col] = v;
        else     xnb[grow * DIM + col] = __float2bfloat16(v);
      }
    }
  }
}

// ---------------------------------------------------------------------------
extern "C" void kernel_launch(void* const* d_in, const int* in_sizes, int n_in,
                              void* d_out, int out_size, void* d_ws, size_t ws_size,
                              hipStream_t stream) {
  const float* x    = (const float*)d_in[0];
  const int*   ei   = (const int*)d_in[1];
  const int*   attr = (const int*)d_in[2];
  const float* Ws   = (const float*)d_in[3];
  const float* bs   = (const float*)d_in[4];
  const float* Wk   = (const float*)d_in[5];
  const float* bk   = (const float*)d_in[6];
  const float* eps  = (const float*)d_in[7];
  float* out = (float*)d_out;

  char* ws = (char*)d_ws;
  size_t off = 0;
  auto alloc = [&](size_t bytes) { char* p = ws + off; off += (bytes + 255) & ~(size_t)255; return p; };
  const size_t ROWB = (size_t)NROWP * DIM * 2;
  __hip_bfloat16* xb0 = (__hip_bfloat16*)alloc(ROWB);
  __hip_bfloat16* xb1 = (__hip_bfloat16*)alloc(ROWB);
  __hip_bfloat16* xb2 = (__hip_bfloat16*)alloc(ROWB);
  __hip_bfloat16* ag0 = (__hip_bfloat16*)alloc(ROWB);
  __hip_bfloat16* ag1 = (__hip_bfloat16*)alloc(ROWB);
  __hip_bfloat16* ag2 = (__hip_bfloat16*)alloc(ROWB);
  __hip_bfloat16* WT  = (__hip_bfloat16*)alloc(12 * 16384 * 2);
  int* cursor    = (int*)alloc((size_t)NB3 * 4);
  int* rowptr    = (int*)alloc((size_t)(NB3 + 1) * 4);
  int* blocksums = (int*)alloc(1024 * 4);
  int* G         = (int*)alloc((size_t)SORTN * 4);
  int* bsum2     = (int*)alloc(1024 * 4);
  int* wl        = (int*)alloc((size_t)NB3 * 4);
  int* csr_src   = (int*)alloc((size_t)(EDGES + 4 * NB3 + 16) * 4);

  int egrid  = (EDGES + 255) / 256;        // 3125
  int igrid  = (int)(ND / 4 / 256);        // 6250 (covers 600 needed for aux work)
  int fgrid  = (SORTN + 255) / 256;        // 441

  hipLaunchKernelGGL(init_kernel, dim3(igrid), dim3(256), 0, stream,
                     x, Ws, Wk, xb0, xb1, xb2, WT, cursor);
  hipLaunchKernelGGL(hist_kernel, dim3(egrid), dim3(256), 0, stream, ei, attr, cursor, EDGES);
  hipLaunchKernelGGL(scan_a_kernel, dim3(NBLKS), dim3(256), 0, stream, cursor, rowptr, blocksums, NB3);
  hipLaunchKernelGGL(scan_b_kernel, dim3(1), dim3(256), 0, stream, blocksums, NBLKS);
  hipLaunchKernelGGL(scanc_bhist_kernel, dim3(NBLKS), dim3(256), 0, stream,
                     rowptr, cursor, blocksums, csr_src, G, NB3);
  hipLaunchKernelGGL(fill_kernel, dim3(egrid * NPART), dim3(256), 0, stream, ei, attr, cursor, csr_src, EDGES);
  hipLaunchKernelGGL(fscan_a_kernel, dim3(fgrid), dim3(256), 0, stream, G, G, bsum2, SORTN);
  hipLaunchKernelGGL(scan_b_kernel, dim3(1), dim3(256), 0, stream, bsum2, fgrid);
  hipLaunchKernelGGL(bfill_kernel, dim3(NBLKS), dim3(256), 0, stream, rowptr, G, bsum2, wl);

  int ggrid = (NODES + 63) / 64;
  auto glaunch = [&](int nwork, const __hip_bfloat16* s0, const __hip_bfloat16* s1,
                     const __hip_bfloat16* s2) {
    int blocks = (nwork * 16 + 255) / 256;
    hipLaunchKernelGGL(gather_kernel, dim3(blocks), dim3(256), 0, stream,
                       s0, s1, s2, rowptr, csr_src, wl, ag0, ag1, ag2, nwork);
  };

  // Layer 0
  glaunch(NODES, xb0, nullptr, nullptr);
  hipLaunchKernelGGL(lgemm_kernel, dim3(ggrid), dim3(256), 0, stream,
                     xb0, ag0, ag1, ag2, WT, bs + 0, bk + 0, eps + 0,
                     xb1, (float*)nullptr, 0);
  // Layer 1
  glaunch(2 * NODES, xb1, xb0, nullptr);
  hipLaunchKernelGGL(lgemm_kernel, dim3(ggrid), dim3(256), 0, stream,
                     xb1, ag0, ag1, ag2, WT, bs + 128, bk + 3 * 128, eps + 1,
                     xb2, (float*)nullptr, 1);
  // Layer 2
  glaunch(3 * NODES, xb2, xb1, xb0);
  hipLaunchKernelGGL(lgemm_kernel, dim3(ggrid), dim3(256), 0, stream,
                     xb2, ag0, ag1, ag2, WT, bs + 256, bk + 6 * 128, eps + 2,
                     (__hip_bfloat16*)nullptr, out, 2);
}

// Round 10
// 329.974 us; speedup vs baseline: 3.2896x; 1.0200x over previous
//
#include <hip/hip_runtime.h>
#include <hip/hip_bf16.h>

// DRew-GIN: N=50000, E=800000, D=128, L=3, NU=1.
// R10: source-major gather scheduling (each gather launch reads ONE 12.8MB
//      tensor; worklist prefixes give the bucket subsets), fill NPART=4,
//      32 sort classes. 15 launches.

#define NODES 50000
#define EDGES 800000
#define DIM   128
#define ND    ((long)NODES * DIM)
#define NB3   (3 * NODES)            // buckets: d*3 + (k-1)
#define NPART 4
#define PSIZE (NODES / NPART)        // 12500
#define NROWP 50048                  // row-padded tensors (tail tile slack)
#define NBLKS ((NB3 + 255) / 256)    // 587
#define NCELL 96                     // 3 km1 * 32 size classes
#define SORTN (NCELL * NBLKS)        // 56352

typedef __attribute__((ext_vector_type(8))) short  bf16x8;
typedef __attribute__((ext_vector_type(4))) float  f32x4;

#define LDS_STRIDE 136   // bf16 elements; 272B rows

// ---------------------------------------------------------------------------
// init: x->bf16 shadow, weight conversion, dummy-row zero, cursor zero.
__global__ __launch_bounds__(256) void init_kernel(
    const float* __restrict__ x, const float* __restrict__ Ws,
    const float* __restrict__ Wk, __hip_bfloat16* __restrict__ xb0,
    __hip_bfloat16* __restrict__ xb1, __hip_bfloat16* __restrict__ xb2,
    __hip_bfloat16* __restrict__ WT, int* __restrict__ cursor) {
  int b = blockIdx.x, tid = threadIdx.x;
  long i = (long)b * 256 + tid;
  if (i < ND / 4) {
    float4 v = ((const float4*)x)[i];
    union { __hip_bfloat16 h[4]; uint2 u; } pk;
    pk.h[0] = __float2bfloat16(v.x); pk.h[1] = __float2bfloat16(v.y);
    pk.h[2] = __float2bfloat16(v.z); pk.h[3] = __float2bfloat16(v.w);
    ((uint2*)xb0)[i] = pk.u;
  }
  if (b < 12) {
    const float* src = (b < 3) ? (Ws + (long)b * 16384) : (Wk + (long)(b - 3) * 16384);
    __hip_bfloat16* dst = WT + (long)b * 16384;
    for (int idx = tid; idx < 16384; idx += 256) {
      int k = idx >> 7, n = idx & 127;
      dst[n * 128 + k] = __float2bfloat16(src[idx]);
    }
  }
  if (b >= 12 && b < 12 + NBLKS) {
    int g = (b - 12) * 256 + tid;
    if (g < NB3) cursor[g] = 0;
  }
  if (b == 599 && tid < DIM) {
    xb0[(long)NODES * DIM + tid] = __float2bfloat16(0.f);
    xb1[(long)NODES * DIM + tid] = __float2bfloat16(0.f);
    xb2[(long)NODES * DIM + tid] = __float2bfloat16(0.f);
  }
}

// ---------------------------------------------------------------------------
// CSR build (pad-to-4).
__global__ __launch_bounds__(256) void hist_kernel(
    const int* __restrict__ ei, const int* __restrict__ attr,
    int* __restrict__ counts, int E) {
  int e = blockIdx.x * 256 + threadIdx.x;
  if (e >= E) return;
  atomicAdd(&counts[ei[E + e] * 3 + (attr[e] - 1)], 1);
}

__global__ __launch_bounds__(256) void scan_a_kernel(
    const int* __restrict__ counts, int* __restrict__ partial,
    int* __restrict__ blocksums, int n) {
  __shared__ int tmp[256];
  int gid = blockIdx.x * 256 + threadIdx.x;
  int v = (gid < n) ? ((counts[gid] + 3) & ~3) : 0;
  tmp[threadIdx.x] = v;
  __syncthreads();
  for (int off = 1; off < 256; off <<= 1) {
    int t = (threadIdx.x >= off) ? tmp[threadIdx.x - off] : 0;
    __syncthreads();
    tmp[threadIdx.x] += t;
    __syncthreads();
  }
  if (gid < n) partial[gid] = tmp[threadIdx.x] - v;
  if (threadIdx.x == 255) blocksums[blockIdx.x] = tmp[255];
}

__global__ __launch_bounds__(256) void scan_b_kernel(int* __restrict__ bs, int nb) {
  __shared__ int tmp[256];
  __shared__ int carry;
  if (threadIdx.x == 0) carry = 0;
  __syncthreads();
  for (int base = 0; base < nb; base += 256) {
    int gid = base + threadIdx.x;
    int v = (gid < nb) ? bs[gid] : 0;
    tmp[threadIdx.x] = v;
    __syncthreads();
    for (int off = 1; off < 256; off <<= 1) {
      int t = (threadIdx.x >= off) ? tmp[threadIdx.x - off] : 0;
      __syncthreads();
      tmp[threadIdx.x] += t;
      __syncthreads();
    }
    if (gid < nb) bs[gid] = tmp[threadIdx.x] - v + carry;
    __syncthreads();
    if (threadIdx.x == 0) carry += tmp[255];
    __syncthreads();
  }
}

// scan_c + sort histogram fused. cell = km1*32 + (31 - min(pcnt/4,31)).
__global__ __launch_bounds__(256) void scanc_bhist_kernel(
    int* __restrict__ rowptr, int* __restrict__ cursor,
    const int* __restrict__ bs, int* __restrict__ csr,
    int* __restrict__ G, int n) {
  __shared__ int h[NCELL];
  if (threadIdx.x < NCELL) h[threadIdx.x] = 0;
  __syncthreads();
  int gid = blockIdx.x * 256 + threadIdx.x;
  if (gid < n) {
    int cnt = cursor[gid];
    int pcnt = (cnt + 3) & ~3;
    int val = rowptr[gid] + bs[blockIdx.x];
    rowptr[gid] = val;
    cursor[gid] = val;
    for (int i = cnt; i < pcnt; ++i) csr[val + i] = NODES;
    if (gid == n - 1) rowptr[n] = val + pcnt;
    int c = pcnt >> 2; if (c > 31) c = 31;
    int km1 = gid - (gid / 3) * 3;
    atomicAdd(&h[km1 * 32 + (31 - c)], 1);
  }
  __syncthreads();
  if (threadIdx.x < NCELL) G[threadIdx.x * NBLKS + blockIdx.x] = h[threadIdx.x];
}

__global__ __launch_bounds__(256) void fill_kernel(
    const int* __restrict__ ei, const int* __restrict__ attr,
    int* __restrict__ cursor, int* __restrict__ csr_src, int E) {
  int p = blockIdx.x & (NPART - 1);
  int chunk = blockIdx.x >> 2;
  int e = chunk * 256 + threadIdx.x;
  if (e >= E) return;
  int d = ei[E + e];
  int lo = p * PSIZE;
  if (d < lo || d >= lo + PSIZE) return;
  int pos = atomicAdd(&cursor[d * 3 + (attr[e] - 1)], 1);
  csr_src[pos] = ei[e];
}

// Flat exclusive scan pass 1 (in-place ok).
__global__ __launch_bounds__(256) void fscan_a_kernel(
    const int* __restrict__ in, int* __restrict__ partial,
    int* __restrict__ blocksums, int n) {
  __shared__ int tmp[256];
  int gid = blockIdx.x * 256 + threadIdx.x;
  int v = (gid < n) ? in[gid] : 0;
  tmp[threadIdx.x] = v;
  __syncthreads();
  for (int off = 1; off < 256; off <<= 1) {
    int t = (threadIdx.x >= off) ? tmp[threadIdx.x - off] : 0;
    __syncthreads();
    tmp[threadIdx.x] += t;
    __syncthreads();
  }
  if (gid < n) partial[gid] = tmp[threadIdx.x] - v;
  if (threadIdx.x == 255) blocksums[blockIdx.x] = tmp[255];
}

// bfill with blocksum add folded in.
__global__ __launch_bounds__(256) void bfill_kernel(
    const int* __restrict__ rowptr, const int* __restrict__ G,
    const int* __restrict__ bsum2, int* __restrict__ wl) {
  __shared__ int base[NCELL];
  if (threadIdx.x < NCELL) {
    int gidx = threadIdx.x * NBLKS + blockIdx.x;
    base[threadIdx.x] = G[gidx] + bsum2[gidx >> 8];
  }
  __syncthreads();
  int b = blockIdx.x * 256 + threadIdx.x;
  if (b >= NB3) return;
  int pcnt = rowptr[b + 1] - rowptr[b];
  int c = pcnt >> 2; if (c > 31) c = 31;
  int km1 = b - (b / 3) * 3;
  int pos = atomicAdd(&base[km1 * 32 + (31 - c)], 1);  // LDS atomic
  wl[pos] = b;
}

// ---------------------------------------------------------------------------
// Gather: SINGLE source tensor; bucket km1 selects the output buffer only.
// wl is km1-major big-first, so nwork = N / 2N / 3N selects km1 prefixes.
__global__ __launch_bounds__(256, 6) void gather_kernel(
    const __hip_bfloat16* __restrict__ src,
    const int* __restrict__ rowptr, const int* __restrict__ csr,
    const int* __restrict__ wl,
    __hip_bfloat16* __restrict__ ag0, __hip_bfloat16* __restrict__ ag1,
    __hip_bfloat16* __restrict__ ag2, int nwork) {
  int group = (blockIdx.x * 256 + threadIdx.x) >> 4;
  int lane16 = threadIdx.x & 15;
  if (group >= nwork) return;
  int b = wl[group];
  int d = b / 3;
  int km1 = b - d * 3;
  __hip_bfloat16* ag = (km1 == 0) ? ag0 : ((km1 == 1) ? ag1 : ag2);
  int beg = rowptr[b], end = rowptr[b + 1];   // (end-beg)%4 == 0
  float a0 = 0.f, a1 = 0.f, a2 = 0.f, a3 = 0.f,
        a4 = 0.f, a5 = 0.f, a6 = 0.f, a7 = 0.f;
  for (int base = beg; base < end; base += 16) {
    int idxv = csr[base + lane16];            // slack-allocated
    int cnt = end - base; if (cnt > 16) cnt = 16;
    for (int j = 0; j < cnt; j += 4) {
      int q0 = __shfl(idxv, j + 0, 16);
      int q1 = __shfl(idxv, j + 1, 16);
      int q2 = __shfl(idxv, j + 2, 16);
      int q3 = __shfl(idxv, j + 3, 16);
      uint4 v0 = *(const uint4*)(src + (long)q0 * DIM + lane16 * 8);
      uint4 v1 = *(const uint4*)(src + (long)q1 * DIM + lane16 * 8);
      uint4 v2 = *(const uint4*)(src + (long)q2 * DIM + lane16 * 8);
      uint4 v3 = *(const uint4*)(src + (long)q3 * DIM + lane16 * 8);
      a0 += __uint_as_float(v0.x << 16) + __uint_as_float(v1.x << 16)
          + __uint_as_float(v2.x << 16) + __uint_as_float(v3.x << 16);
      a1 += __uint_as_float(v0.x & 0xffff0000u) + __uint_as_float(v1.x & 0xffff0000u)
          + __uint_as_float(v2.x & 0xffff0000u) + __uint_as_float(v3.x & 0xffff0000u);
      a2 += __uint_as_float(v0.y << 16) + __uint_as_float(v1.y << 16)
          + __uint_as_float(v2.y << 16) + __uint_as_float(v3.y << 16);
      a3 += __uint_as_float(v0.y & 0xffff0000u) + __uint_as_float(v1.y & 0xffff0000u)
          + __uint_as_float(v2.y & 0xffff0000u) + __uint_as_float(v3.y & 0xffff0000u);
      a4 += __uint_as_float(v0.z << 16) + __uint_as_float(v1.z << 16)
          + __uint_as_float(v2.z << 16) + __uint_as_float(v3.z << 16);
      a5 += __uint_as_float(v0.z & 0xffff0000u) + __uint_as_float(v1.z & 0xffff0000u)
          + __uint_as_float(v2.z & 0xffff0000u) + __uint_as_float(v3.z & 0xffff0000u);
      a6 += __uint_as_float(v0.w << 16) + __uint_as_float(v1.w << 16)
          + __uint_as_float(v2.w << 16) + __uint_as_float(v3.w << 16);
      a7 += __uint_as_float(v0.w & 0xffff0000u) + __uint_as_float(v1.w & 0xffff0000u)
          + __uint_as_float(v2.w & 0xffff0000u) + __uint_as_float(v3.w & 0xffff0000u);
    }
  }
  union { __hip_bfloat16 h[8]; uint4 u; } pk;
  pk.h[0] = __float2bfloat16(a0); pk.h[1] = __float2bfloat16(a1);
  pk.h[2] = __float2bfloat16(a2); pk.h[3] = __float2bfloat16(a3);
  pk.h[4] = __float2bfloat16(a4); pk.h[5] = __float2bfloat16(a5);
  pk.h[6] = __float2bfloat16(a6); pk.h[7] = __float2bfloat16(a7);
  *(uint4*)(ag + (long)d * DIM + lane16 * 8) = pk.u;
}

// ---------------------------------------------------------------------------
// Layer GEMM: bf16 node state, A-frags direct from global, B in LDS.
__global__ __launch_bounds__(256, 4) void lgemm_kernel(
    const __hip_bfloat16* __restrict__ xbSelf,
    const __hip_bfloat16* __restrict__ ag0,
    const __hip_bfloat16* __restrict__ ag1,
    const __hip_bfloat16* __restrict__ ag2,
    const __hip_bfloat16* __restrict__ WT,
    const float* __restrict__ bs_t,
    const float* __restrict__ bk_t,
    const float* __restrict__ epsp,
    __hip_bfloat16* __restrict__ xnb,   // bf16 out (layers 0/1)
    float* __restrict__ xn,             // f32 out (final layer) or null
    int t) {
  __shared__ __hip_bfloat16 b_lds[128 * LDS_STRIDE];  // 34816 B

  int tid = threadIdx.x;
  long row0 = (long)blockIdx.x * 64;
  int wave = tid >> 6, lane = tid & 63;
  int l15 = lane & 15, q = lane >> 4;
  long arow = row0 + wave * 16 + l15;

  const __hip_bfloat16* Asrc[4] = {xbSelf, ag0, ag1, ag2};
  f32x4 out[8];

  for (int p = 0; p <= t + 1; ++p) {
    if (p > 0) __syncthreads();
    const __hip_bfloat16* Am = Asrc[p];
    uint4 af[4];
#pragma unroll
    for (int k0i = 0; k0i < 4; ++k0i)
      af[k0i] = *(const uint4*)(Am + arow * DIM + k0i * 32 + 8 * q);
    const __hip_bfloat16* W = (p == 0) ? (WT + (long)t * 16384)
                                       : (WT + (long)(3 + t * 3 + (p - 1)) * 16384);
    {
      const uint4* bq = (const uint4*)W;
#pragma unroll
      for (int i = 0; i < 8; ++i) {
        int idx = tid + 256 * i;
        int n = idx >> 4, k8 = idx & 15;
        uint4 v = bq[idx];
        *(uint4*)(b_lds + n * LDS_STRIDE + k8 * 8) = v;
      }
    }
    __syncthreads();

    f32x4 acc[8] = {};
#pragma unroll
    for (int k0i = 0; k0i < 4; ++k0i) {
      bf16x8 a = __builtin_bit_cast(bf16x8, af[k0i]);
#pragma unroll
      for (int j = 0; j < 8; ++j) {
        bf16x8 bfr = *(const bf16x8*)(b_lds + (16 * j + l15) * LDS_STRIDE + k0i * 32 + 8 * q);
        acc[j] = __builtin_amdgcn_mfma_f32_16x16x32_bf16(a, bfr, acc[j], 0, 0, 0);
      }
    }
    if (p == 0) {
      float sc = 1.0f + *epsp;
#pragma unroll
      for (int j = 0; j < 8; ++j) {
        float b = bs_t[16 * j + l15];
#pragma unroll
        for (int r = 0; r < 4; ++r) out[j][r] = sc * fmaxf(acc[j][r] + b, 0.f);
      }
    } else {
      const float* bb = bk_t + (p - 1) * 128;
#pragma unroll
      for (int j = 0; j < 8; ++j) {
        float b = bb[16 * j + l15];
#pragma unroll
        for (int r = 0; r < 4; ++r) out[j][r] += fmaxf(acc[j][r] + b, 0.f);
      }
    }
  }

  long rbase = row0 + wave * 16 + q * 4;
  bool fin = (xn != nullptr);
#pragma unroll
  for (int j = 0; j < 8; ++j) {
    int col = 16 * j + l15;
#pragma unroll
    for (int r = 0; r < 4; ++r) {
      long grow = rbase + r;
      if (grow < NODES) {
        float res = __bfloat162float(xbSelf[grow * DIM + col]);
        float v = res + fmaxf(out[j][r], 0.f);
        if (fin) xn[grow * DIM + col] = v;
        else     xnb[grow * DIM + col] = __float2bfloat16(v);
      }
    }
  }
}

// ---------------------------------------------------------------------------
extern "C" void kernel_launch(void* const* d_in, const int* in_sizes, int n_in,
                              void* d_out, int out_size, void* d_ws, size_t ws_size,
                              hipStream_t stream) {
  const float* x    = (const float*)d_in[0];
  const int*   ei   = (const int*)d_in[1];
  const int*   attr = (const int*)d_in[2];
  const float* Ws   = (const float*)d_in[3];
  const float* bs   = (const float*)d_in[4];
  const float* Wk   = (const float*)d_in[5];
  const float* bk   = (const float*)d_in[6];
  const float* eps  = (const float*)d_in[7];
  float* out = (float*)d_out;

  char* ws = (char*)d_ws;
  size_t off = 0;
  auto alloc = [&](size_t bytes) { char* p = ws + off; off += (bytes + 255) & ~(size_t)255; return p; };
  const size_t ROWB = (size_t)NROWP * DIM * 2;
  __hip_bfloat16* xb0  = (__hip_bfloat16*)alloc(ROWB);
  __hip_bfloat16* xb1  = (__hip_bfloat16*)alloc(ROWB);
  __hip_bfloat16* xb2  = (__hip_bfloat16*)alloc(ROWB);
  __hip_bfloat16* agA0 = (__hip_bfloat16*)alloc(ROWB);  // src xb0: layer0 k=1
  __hip_bfloat16* agA1 = (__hip_bfloat16*)alloc(ROWB);  // src xb0: layer1 k=2
  __hip_bfloat16* agA2 = (__hip_bfloat16*)alloc(ROWB);  // src xb0: layer2 k=3
  __hip_bfloat16* agB0 = (__hip_bfloat16*)alloc(ROWB);  // src xb1: layer1 k=1
  __hip_bfloat16* agB1 = (__hip_bfloat16*)alloc(ROWB);  // src xb1: layer2 k=2
  __hip_bfloat16* agC0 = (__hip_bfloat16*)alloc(ROWB);  // src xb2: layer2 k=1
  __hip_bfloat16* WT   = (__hip_bfloat16*)alloc(12 * 16384 * 2);
  int* cursor    = (int*)alloc((size_t)NB3 * 4);
  int* rowptr    = (int*)alloc((size_t)(NB3 + 1) * 4);
  int* blocksums = (int*)alloc(1024 * 4);
  int* G         = (int*)alloc((size_t)SORTN * 4);
  int* bsum2     = (int*)alloc(1024 * 4);
  int* wl        = (int*)alloc((size_t)NB3 * 4);
  int* csr_src   = (int*)alloc((size_t)(EDGES + 4 * NB3 + 16) * 4);

  int egrid  = (EDGES + 255) / 256;        // 3125
  int igrid  = (int)(ND / 4 / 256);        // 6250
  int fgrid  = (SORTN + 255) / 256;        // 221

  hipLaunchKernelGGL(init_kernel, dim3(igrid), dim3(256), 0, stream,
                     x, Ws, Wk, xb0, xb1, xb2, WT, cursor);
  hipLaunchKernelGGL(hist_kernel, dim3(egrid), dim3(256), 0, stream, ei, attr, cursor, EDGES);
  hipLaunchKernelGGL(scan_a_kernel, dim3(NBLKS), dim3(256), 0, stream, cursor, rowptr, blocksums, NB3);
  hipLaunchKernelGGL(scan_b_kernel, dim3(1), dim3(256), 0, stream, blocksums, NBLKS);
  hipLaunchKernelGGL(scanc_bhist_kernel, dim3(NBLKS), dim3(256), 0, stream,
                     rowptr, cursor, blocksums, csr_src, G, NB3);
  hipLaunchKernelGGL(fill_kernel, dim3(egrid * NPART), dim3(256), 0, stream, ei, attr, cursor, csr_src, EDGES);
  hipLaunchKernelGGL(fscan_a_kernel, dim3(fgrid), dim3(256), 0, stream, G, G, bsum2, SORTN);
  hipLaunchKernelGGL(scan_b_kernel, dim3(1), dim3(256), 0, stream, bsum2, fgrid);
  hipLaunchKernelGGL(bfill_kernel, dim3(NBLKS), dim3(256), 0, stream, rowptr, G, bsum2, wl);

  int ggrid = (NODES + 63) / 64;
  auto glaunch = [&](int nwork, const __hip_bfloat16* src, __hip_bfloat16* a0,
                     __hip_bfloat16* a1, __hip_bfloat16* a2) {
    int blocks = (nwork * 16 + 255) / 256;
    hipLaunchKernelGGL(gather_kernel, dim3(blocks), dim3(256), 0, stream,
                       src, rowptr, csr_src, wl, a0, a1, a2, nwork);
  };

  // Gather A: all buckets from xb0 (km1=0 -> agA0, km1=1 -> agA1, km1=2 -> agA2).
  glaunch(3 * NODES, xb0, agA0, agA1, agA2);
  // Layer 0: uses agA0.
  hipLaunchKernelGGL(lgemm_kernel, dim3(ggrid), dim3(256), 0, stream,
                     xb0, agA0, agA0, agA0, WT, bs + 0, bk + 0, eps + 0,
                     xb1, (float*)nullptr, 0);
  // Gather B: km1 in {0,1} from xb1.
  glaunch(2 * NODES, xb1, agB0, agB1, agB1);
  // Layer 1: k=1 -> agB0 (src xb1), k=2 -> agA1 (src xb0).
  hipLaunchKernelGGL(lgemm_kernel, dim3(ggrid), dim3(256), 0, stream,
                     xb1, agB0, agA1, agA1, WT, bs + 128, bk + 3 * 128, eps + 1,
                     xb2, (float*)nullptr, 1);
  // Gather C: km1=0 from xb2.
  glaunch(NODES, xb2, agC0, agC0, agC0);
  // Layer 2: k=1 -> agC0 (xb2), k=2 -> agB1 (xb1), k=3 -> agA2 (xb0).
  hipLaunchKernelGGL(lgemm_kernel, dim3(ggrid), dim3(256), 0, stream,
                     xb2, agC0, agB1, agA2, WT, bs + 256, bk + 6 * 128, eps + 2,
                     (__hip_bfloat16*)nullptr, out, 2);
}